// Round 4
// baseline (48.150 us; speedup 1.0000x reference)
//
#include <hip/hip_runtime.h>

#define NB 8
#define NS 4
#define NN 8192
#define NM 50
#define K10 10
#define THREADS 256
#define COST_THRESH 50.0f
#define LOSS_BLOCKS 256
#define NBUCK 1024
#define CAP 256
#define TOTAL (NB * NS * NN)

__device__ __forceinline__ bool lexless(float d1, int i1, float d2, int i2) {
  // matches jax.lax.top_k ordering on -dist: (dist asc, index asc)
  return (d1 < d2) || (d1 == d2 && i1 < i2);
}

// Clear assign, zero scalars, and pack pred xyz into SoA streams:
// packed[c*TOTAL + i], i = bs*NN + n. Bit-exact copy.
__global__ void __launch_bounds__(256) prep_kernel(
    const float* __restrict__ pred_boxes, float* __restrict__ packed,
    int* __restrict__ assign, float* __restrict__ acc,
    int* __restrict__ bs_unm, int* __restrict__ done) {
  int i = blockIdx.x * blockDim.x + threadIdx.x;
  for (int j = i; j < TOTAL; j += gridDim.x * blockDim.x) {
    assign[j] = -1;
    packed[j] = pred_boxes[j * 7 + 0];
    packed[TOTAL + j] = pred_boxes[j * 7 + 1];
    packed[2 * TOTAL + j] = pred_boxes[j * 7 + 2];
  }
  if (i == 0) { acc[0] = 0.0f; *done = 0; }
  if (i >= 64 && i < 64 + NB * NS) bs_unm[i - 64] = 0;
}

// One block per (b, s, m): exact top-10 nearest preds by (dist, idx) via
// histogram-select on d^2 (monotone in dist). masked top-10 = {entries with
// dist < 50} (subset property), unmatched top-5 = first 5 of raw top-10.
__global__ void __launch_bounds__(256) topk_kernel(
    const float* __restrict__ packed, const float* __restrict__ pred_scores,
    const float* __restrict__ gt_boxes, const int* __restrict__ n_gt,
    int* __restrict__ assign, float* __restrict__ per_gt_sum,
    int* __restrict__ bs_unm) {
  const int blk = blockIdx.x;      // b*NS*NM + s*NM + m
  const int m = blk % NM;
  const int bs = blk / NM;
  const int b = bs / NS;
  const int t = threadIdx.x;

  __shared__ float sd2[NN];        // 32 KB: d^2 per pred
  __shared__ int shist[NBUCK];     // 4 KB
  __shared__ float scd[CAP];       // candidate d^2 -> later sqrt'd dist
  __shared__ int sci[CAP];         // candidate idx
  __shared__ float sred[16];       // min/max staging
  __shared__ float sbb[2];         // bmin, scale
  __shared__ int scnt;
  __shared__ int sbucket;
  __shared__ float soutd[K10];
  __shared__ int souti[K10];

  for (int i = t; i < NBUCK; i += THREADS) shist[i] = 0;
  if (t == 0) { scnt = 0; sbucket = NBUCK - 2; }

  const float gx = gt_boxes[(b * NM + m) * 7 + 0];
  const float gy = gt_boxes[(b * NM + m) * 7 + 1];
  const float gz = gt_boxes[(b * NM + m) * 7 + 2];
  const bool valid = (m < n_gt[b]);

  const float* px = packed + (size_t)bs * NN;
  const float* py = px + TOTAL;
  const float* pz = py + TOTAL;

  // P1: d^2 for all preds -> LDS; track min/max
  float lmin = INFINITY, lmax = 0.0f;
#pragma unroll
  for (int k = 0; k < NN / THREADS; k++) {
    int n = t + k * THREADS;
    float dx = px[n] - gx;
    float dy = py[n] - gy;
    float dz = pz[n] - gz;
    float d2 = dx * dx + dy * dy + dz * dz;
    sd2[n] = d2;
    lmin = fminf(lmin, d2);
    lmax = fmaxf(lmax, d2);
  }
#pragma unroll
  for (int off = 32; off >= 1; off >>= 1) {
    lmin = fminf(lmin, __shfl_down(lmin, off));
    lmax = fmaxf(lmax, __shfl_down(lmax, off));
  }
  int wave = t >> 6;
  if ((t & 63) == 0) { sred[wave] = lmin; sred[8 + wave] = lmax; }
  __syncthreads();
  if (t == 0) {
    float bmin = fminf(fminf(sred[0], sred[1]), fminf(sred[2], sred[3]));
    float bmax = fmaxf(fmaxf(sred[8], sred[9]), fmaxf(sred[10], sred[11]));
    sbb[0] = bmin;
    sbb[1] = (float)NBUCK / fmaxf(bmax - bmin, 1e-30f);
  }
  __syncthreads();
  const float bmin = sbb[0], scale = sbb[1];

  // P2: histogram on d^2
#pragma unroll
  for (int k = 0; k < NN / THREADS; k++) {
    int n = t + k * THREADS;
    int bidx = (int)((sd2[n] - bmin) * scale);
    bidx = min(NBUCK - 1, max(0, bidx));
    atomicAdd(&shist[bidx], 1);
  }
  __syncthreads();

  // P3: first bucket j with cumulative count >= 10 (single wave)
  if (t < 64) {
    int lsum = 0;
    for (int i = 0; i < NBUCK / 64; i++) lsum += shist[t * (NBUCK / 64) + i];
    int incl = lsum;
#pragma unroll
    for (int off = 1; off < 64; off <<= 1) {
      int v = __shfl_up(incl, off);
      if (t >= off) incl += v;
    }
    int excl = incl - lsum;
    if (excl < K10 && incl >= K10) {
      int c = excl;
      for (int i = 0; i < NBUCK / 64; i++) {
        c += shist[t * (NBUCK / 64) + i];
        if (c >= K10) { sbucket = t * (NBUCK / 64) + i; break; }
      }
    }
  }
  __syncthreads();
  // hi-edge of bucket j+1 plus half-bin margin (covers edge rounding + sqrt-ties)
  const float bound = bmin + ((float)(sbucket + 2) + 0.5f) / scale;

  // P4: collect candidates below bound (superset of exact top-10)
#pragma unroll
  for (int k = 0; k < NN / THREADS; k++) {
    int n = t + k * THREADS;
    float d2 = sd2[n];
    if (d2 < bound) {
      int p = atomicAdd(&scnt, 1);
      if (p < CAP) { scd[p] = d2; sci[p] = n; }
    }
  }
  __syncthreads();
  const int K = min(scnt, CAP);

  // P5: sqrt candidates (matches reference dist exactly), exact rank by (d, idx)
  for (int c = t; c < K; c += THREADS) scd[c] = sqrtf(scd[c]);
  __syncthreads();
  for (int c = t; c < K; c += THREADS) {
    float dc = scd[c];
    int ic = sci[c];
    int rank = 0;
    for (int o = 0; o < K; o++) rank += lexless(scd[o], sci[o], dc, ic) ? 1 : 0;
    if (rank < K10) { soutd[rank] = dc; souti[rank] = ic; }
  }
  __syncthreads();

  // epilogue on wave 0: lanes 0..9 scatter, lanes 0..4 unmatched term
  if (t < 64) {
    bool pick = (t < K10) && valid && (soutd[t] < COST_THRESH);
    if (pick) atomicMax(&assign[(size_t)bs * NN + souti[t]], m);
    bool matched = __any(pick);
    if (valid && !matched) {
      float a = 0.0f;
      if (t < 5) a = expf(-0.5f * soutd[t]) * (1.0f - pred_scores[(size_t)bs * NN + souti[t]]);
#pragma unroll
      for (int off = 8; off >= 1; off >>= 1) a += __shfl_down(a, off);
      if (t == 0) {
        atomicAdd(per_gt_sum, a * 0.2f);
        atomicOr(&bs_unm[bs], 1);
      }
    }
  }
}

// Fused loss reduction + final combine (last-block ticket).
__global__ void __launch_bounds__(256) loss_final_kernel(
    const float* __restrict__ packed, const float* __restrict__ pred_scores,
    const float* __restrict__ gt_boxes, const int* __restrict__ assign,
    float* __restrict__ partials, int* __restrict__ done,
    const float* __restrict__ acc, const int* __restrict__ bs_unm,
    const float* __restrict__ wc, const float* __restrict__ wo,
    const float* __restrict__ wu, float* __restrict__ out) {
  int tid = blockIdx.x * blockDim.x + threadIdx.x;
  float lc = 0.0f, spp = 0.0f, spn = 0.0f, np = 0.0f;
  for (int i = tid; i < TOTAL; i += gridDim.x * blockDim.x) {
    int a = assign[i];
    float x = pred_scores[i];
    if (a >= 0) {
      np += 1.0f;
      int b = i / (NS * NN);
      const float* gbp = &gt_boxes[(b * NM + a) * 7];
#pragma unroll
      for (int c = 0; c < 3; c++) {
        float diff = packed[c * TOTAL + i] - gbp[c];
        float ad = fabsf(diff);
        lc += (ad < 1.0f) ? 0.5f * ad * ad : (ad - 0.5f);
      }
      spp += log1pf(expf(-fabsf(x))) + fmaxf(-x, 0.0f);  // softplus(-x)
    } else {
      spn += log1pf(expf(-fabsf(x))) + fmaxf(x, 0.0f);   // softplus(x)
    }
  }
#pragma unroll
  for (int off = 32; off >= 1; off >>= 1) {
    lc += __shfl_down(lc, off);
    spp += __shfl_down(spp, off);
    spn += __shfl_down(spn, off);
    np += __shfl_down(np, off);
  }
  __shared__ float red[4][4];
  __shared__ int s_last;
  int wave = threadIdx.x >> 6;
  if ((threadIdx.x & 63) == 0) {
    red[wave][0] = lc; red[wave][1] = spp; red[wave][2] = spn; red[wave][3] = np;
  }
  __syncthreads();
  if (threadIdx.x == 0) {
    float o0 = 0, o1 = 0, o2 = 0, o3 = 0;
#pragma unroll
    for (int w = 0; w < 4; w++) { o0 += red[w][0]; o1 += red[w][1]; o2 += red[w][2]; o3 += red[w][3]; }
    float* p = &partials[(size_t)blockIdx.x * 8];
    __hip_atomic_store(&p[0], o0, __ATOMIC_RELAXED, __HIP_MEMORY_SCOPE_AGENT);
    __hip_atomic_store(&p[1], o1, __ATOMIC_RELAXED, __HIP_MEMORY_SCOPE_AGENT);
    __hip_atomic_store(&p[2], o2, __ATOMIC_RELAXED, __HIP_MEMORY_SCOPE_AGENT);
    __hip_atomic_store(&p[3], o3, __ATOMIC_RELAXED, __HIP_MEMORY_SCOPE_AGENT);
    __threadfence();
    int ticket = __hip_atomic_fetch_add(done, 1, __ATOMIC_ACQ_REL, __HIP_MEMORY_SCOPE_AGENT);
    s_last = (ticket == gridDim.x - 1) ? 1 : 0;
  }
  __syncthreads();
  if (s_last) {
    __threadfence();
    const int t = threadIdx.x;
    float l0 = __hip_atomic_load(&partials[t * 8 + 0], __ATOMIC_RELAXED, __HIP_MEMORY_SCOPE_AGENT);
    float l1 = __hip_atomic_load(&partials[t * 8 + 1], __ATOMIC_RELAXED, __HIP_MEMORY_SCOPE_AGENT);
    float l2 = __hip_atomic_load(&partials[t * 8 + 2], __ATOMIC_RELAXED, __HIP_MEMORY_SCOPE_AGENT);
    float l3 = __hip_atomic_load(&partials[t * 8 + 3], __ATOMIC_RELAXED, __HIP_MEMORY_SCOPE_AGENT);
#pragma unroll
    for (int off = 32; off >= 1; off >>= 1) {
      l0 += __shfl_down(l0, off);
      l1 += __shfl_down(l1, off);
      l2 += __shfl_down(l2, off);
      l3 += __shfl_down(l3, off);
    }
    __shared__ float red2[4][4];
    if ((t & 63) == 0) {
      red2[t >> 6][0] = l0; red2[t >> 6][1] = l1; red2[t >> 6][2] = l2; red2[t >> 6][3] = l3;
    }
    __syncthreads();
    if (t == 0) {
      float o0 = 0, o1 = 0, o2 = 0, o3 = 0;
#pragma unroll
      for (int w = 0; w < 4; w++) { o0 += red2[w][0]; o1 += red2[w][1]; o2 += red2[w][2]; o3 += red2[w][3]; }
      int ne = 0;
      for (int i = 0; i < NB * NS; i++) ne += bs_unm[i];
      float n_pos = o3;
      float loss_center = o0 / fmaxf(n_pos * 3.0f, 1.0f);
      float n_neg = (float)TOTAL - n_pos;
      float pw = fminf(10.0f, n_neg / fmaxf(n_pos, 1.0f));
      float loss_obj = (pw * o1 + o2) / (float)TOTAL;
      float loss_unm = acc[0] / fmaxf((float)ne, 1.0f);
      out[0] = loss_center * wc[0] + loss_obj * wo[0] + loss_unm * wu[0];
    }
  }
}

extern "C" void kernel_launch(void* const* d_in, const int* in_sizes, int n_in,
                              void* d_out, int out_size, void* d_ws, size_t ws_size,
                              hipStream_t stream) {
  const float* pred_boxes = (const float*)d_in[0];
  // d_in[1] = pred_classes (unused), d_in[4] = gt_classes (unused), d_in[9] = epoch (unused)
  const float* pred_scores = (const float*)d_in[2];
  const float* gt_boxes = (const float*)d_in[3];
  const int* n_gt = (const int*)d_in[5];
  const float* wc = (const float*)d_in[6];
  const float* wo = (const float*)d_in[7];
  const float* wu = (const float*)d_in[8];
  float* out = (float*)d_out;

  char* ws = (char*)d_ws;
  int* assign = (int*)ws;                                   // TOTAL ints (1 MB)
  float* packed = (float*)(ws + (size_t)TOTAL * 4);         // 3*TOTAL floats (3 MB)
  float* acc = (float*)(ws + (size_t)TOTAL * 16);           // acc[0] = per_gt_sum
  int* done = (int*)((char*)acc + 64);
  int* bs_unm = (int*)((char*)acc + 128);                   // NB*NS ints
  float* partials = (float*)((char*)acc + 512);             // LOSS_BLOCKS * 8 floats

  prep_kernel<<<512, 256, 0, stream>>>(pred_boxes, packed, assign, acc, bs_unm, done);
  topk_kernel<<<NB * NS * NM, THREADS, 0, stream>>>(packed, pred_scores, gt_boxes,
                                                    n_gt, assign, &acc[0], bs_unm);
  loss_final_kernel<<<LOSS_BLOCKS, 256, 0, stream>>>(packed, pred_scores, gt_boxes, assign,
                                                     partials, done, acc, bs_unm, wc, wo, wu, out);
}

// Round 5
// 46.493 us; speedup vs baseline: 1.0356x; 1.0356x over previous
//
#include <hip/hip_runtime.h>

#define NB 8
#define NS 4
#define NN 8192
#define NM 50
#define K10 10
#define COST_THRESH 50.0f
#define LOSS_BLOCKS 256
#define NBUCK 1024
#define NSUB 4
#define CAP 256
#define TOTAL (NB * NS * NN)
#define TT 512                 // topk threads
#define ELEMS (NN / TT)        // 16 per thread

__device__ __forceinline__ bool lexless(float d1, int i1, float d2, int i2) {
  // matches jax.lax.top_k ordering on -dist: (dist asc, index asc)
  return (d1 < d2) || (d1 == d2 && i1 < i2);
}

// Clear assign, zero scalars, and pack pred xyz into SoA streams:
// packed[c*TOTAL + i], i = bs*NN + n. Bit-exact copy.
__global__ void __launch_bounds__(256) prep_kernel(
    const float* __restrict__ pred_boxes, float* __restrict__ packed,
    int* __restrict__ assign, float* __restrict__ acc,
    int* __restrict__ bs_unm, int* __restrict__ done) {
  int i = blockIdx.x * blockDim.x + threadIdx.x;
  for (int j = i; j < TOTAL; j += gridDim.x * blockDim.x) {
    assign[j] = -1;
    packed[j] = pred_boxes[j * 7 + 0];
    packed[TOTAL + j] = pred_boxes[j * 7 + 1];
    packed[2 * TOTAL + j] = pred_boxes[j * 7 + 2];
  }
  if (i == 0) { acc[0] = 0.0f; *done = 0; }
  if (i >= 64 && i < 64 + NB * NS) bs_unm[i - 64] = 0;
}

// One block per (b, s, m): exact top-10 nearest preds by (dist, idx) via
// histogram-select on d^2 (monotone in dist), d^2 kept in registers.
// masked top-10 = {entries with dist < 50} (subset property),
// unmatched top-5 = first 5 of raw top-10.
__global__ void __launch_bounds__(TT) topk_kernel(
    const float* __restrict__ packed, const float* __restrict__ pred_scores,
    const float* __restrict__ gt_boxes, const int* __restrict__ n_gt,
    int* __restrict__ assign, float* __restrict__ per_gt_sum,
    int* __restrict__ bs_unm) {
  const int blk = blockIdx.x;      // b*NS*NM + s*NM + m
  const int m = blk % NM;
  const int bs = blk / NM;
  const int b = bs / NS;
  const int t = threadIdx.x;

  __shared__ int shist[NSUB][NBUCK];   // 16 KB
  __shared__ float scd[CAP];
  __shared__ int sci[CAP];
  __shared__ float sred[16];
  __shared__ float sbb[2];
  __shared__ int scnt;
  __shared__ int sbucket;
  __shared__ float soutd[K10];
  __shared__ int souti[K10];

  for (int i = t; i < NSUB * NBUCK; i += TT) ((int*)shist)[i] = 0;
  if (t == 0) { scnt = 0; sbucket = NBUCK - 2; }

  const float gx = gt_boxes[(b * NM + m) * 7 + 0];
  const float gy = gt_boxes[(b * NM + m) * 7 + 1];
  const float gz = gt_boxes[(b * NM + m) * 7 + 2];
  const bool valid = (m < n_gt[b]);

  const float4* px4 = (const float4*)(packed + (size_t)bs * NN);
  const float4* py4 = (const float4*)(packed + TOTAL + (size_t)bs * NN);
  const float4* pz4 = (const float4*)(packed + 2 * TOTAL + (size_t)bs * NN);

  // P1: d^2 into registers; block min/max
  float d2r[ELEMS];
  float lmin = INFINITY, lmax = 0.0f;
#pragma unroll
  for (int c = 0; c < ELEMS / 4; c++) {
    float4 vx = px4[c * TT + t];
    float4 vy = py4[c * TT + t];
    float4 vz = pz4[c * TT + t];
    float dx, dy, dz;
    dx = vx.x - gx; dy = vy.x - gy; dz = vz.x - gz; d2r[c * 4 + 0] = dx * dx + dy * dy + dz * dz;
    dx = vx.y - gx; dy = vy.y - gy; dz = vz.y - gz; d2r[c * 4 + 1] = dx * dx + dy * dy + dz * dz;
    dx = vx.z - gx; dy = vy.z - gy; dz = vz.z - gz; d2r[c * 4 + 2] = dx * dx + dy * dy + dz * dz;
    dx = vx.w - gx; dy = vy.w - gy; dz = vz.w - gz; d2r[c * 4 + 3] = dx * dx + dy * dy + dz * dz;
#pragma unroll
    for (int j = 0; j < 4; j++) {
      lmin = fminf(lmin, d2r[c * 4 + j]);
      lmax = fmaxf(lmax, d2r[c * 4 + j]);
    }
  }
#pragma unroll
  for (int off = 32; off >= 1; off >>= 1) {
    lmin = fminf(lmin, __shfl_down(lmin, off));
    lmax = fmaxf(lmax, __shfl_down(lmax, off));
  }
  const int wave = t >> 6;
  if ((t & 63) == 0) { sred[wave] = lmin; sred[8 + wave] = lmax; }
  __syncthreads();
  if (t == 0) {
    float bmin = INFINITY, bmax = 0.0f;
#pragma unroll
    for (int w = 0; w < TT / 64; w++) {
      bmin = fminf(bmin, sred[w]);
      bmax = fmaxf(bmax, sred[8 + w]);
    }
    sbb[0] = bmin;
    sbb[1] = (float)NBUCK / fmaxf(bmax - bmin, 1e-30f);
  }
  __syncthreads();
  const float bmin = sbb[0], scale = sbb[1];

  // P2: histogram (4 sub-histograms to cut same-bucket atomic contention)
  int* hist = shist[wave & (NSUB - 1)];
#pragma unroll
  for (int e = 0; e < ELEMS; e++) {
    int bidx = (int)((d2r[e] - bmin) * scale);
    bidx = min(NBUCK - 1, max(0, bidx));
    atomicAdd(&hist[bidx], 1);
  }
  __syncthreads();
  // merge sub-histograms into shist[0]
  for (int i = t; i < NBUCK; i += TT)
    shist[0][i] += shist[1][i] + shist[2][i] + shist[3][i];
  __syncthreads();

  // P3: first bucket j with cumulative count >= 10 (single wave)
  if (t < 64) {
    int lsum = 0;
    for (int i = 0; i < NBUCK / 64; i++) lsum += shist[0][t * (NBUCK / 64) + i];
    int incl = lsum;
#pragma unroll
    for (int off = 1; off < 64; off <<= 1) {
      int v = __shfl_up(incl, off);
      if (t >= off) incl += v;
    }
    int excl = incl - lsum;
    if (excl < K10 && incl >= K10) {
      int c = excl;
      for (int i = 0; i < NBUCK / 64; i++) {
        c += shist[0][t * (NBUCK / 64) + i];
        if (c >= K10) { sbucket = t * (NBUCK / 64) + i; break; }
      }
    }
  }
  __syncthreads();
  // hi-edge of bucket j+1 plus half-bin margin (covers edge rounding + sqrt-ties)
  const float bound = bmin + ((float)(sbucket + 2) + 0.5f) / scale;

  // P4: collect candidates below bound (superset of exact top-10)
#pragma unroll
  for (int c = 0; c < ELEMS / 4; c++) {
#pragma unroll
    for (int j = 0; j < 4; j++) {
      float d2 = d2r[c * 4 + j];
      if (d2 < bound) {
        int p = atomicAdd(&scnt, 1);
        if (p < CAP) { scd[p] = d2; sci[p] = (c * TT + t) * 4 + j; }
      }
    }
  }
  __syncthreads();
  const int K = min(scnt, CAP);

  // P5: sqrt candidates (matches reference dist exactly), exact rank by (d, idx)
  for (int c = t; c < K; c += TT) scd[c] = sqrtf(scd[c]);
  __syncthreads();
  for (int c = t; c < K; c += TT) {
    float dc = scd[c];
    int ic = sci[c];
    int rank = 0;
    for (int o = 0; o < K; o++) rank += lexless(scd[o], sci[o], dc, ic) ? 1 : 0;
    if (rank < K10) { soutd[rank] = dc; souti[rank] = ic; }
  }
  __syncthreads();

  // epilogue on wave 0: lanes 0..9 scatter, lanes 0..4 unmatched term
  if (t < 64) {
    bool pick = (t < K10) && valid && (soutd[t] < COST_THRESH);
    if (pick) atomicMax(&assign[(size_t)bs * NN + souti[t]], m);
    bool matched = __any(pick);
    if (valid && !matched) {
      float a = 0.0f;
      if (t < 5) a = expf(-0.5f * soutd[t]) * (1.0f - pred_scores[(size_t)bs * NN + souti[t]]);
#pragma unroll
      for (int off = 8; off >= 1; off >>= 1) a += __shfl_down(a, off);
      if (t == 0) {
        atomicAdd(per_gt_sum, a * 0.2f);
        atomicOr(&bs_unm[bs], 1);
      }
    }
  }
}

// Fused loss reduction + final combine (last-block ticket).
__global__ void __launch_bounds__(256) loss_final_kernel(
    const float* __restrict__ packed, const float* __restrict__ pred_scores,
    const float* __restrict__ gt_boxes, const int* __restrict__ assign,
    float* __restrict__ partials, int* __restrict__ done,
    const float* __restrict__ acc, const int* __restrict__ bs_unm,
    const float* __restrict__ wc, const float* __restrict__ wo,
    const float* __restrict__ wu, float* __restrict__ out) {
  int tid = blockIdx.x * blockDim.x + threadIdx.x;
  float lc = 0.0f, spp = 0.0f, spn = 0.0f, np = 0.0f;
  for (int i = tid; i < TOTAL; i += gridDim.x * blockDim.x) {
    int a = assign[i];
    float x = pred_scores[i];
    if (a >= 0) {
      np += 1.0f;
      int b = i / (NS * NN);
      const float* gbp = &gt_boxes[(b * NM + a) * 7];
#pragma unroll
      for (int c = 0; c < 3; c++) {
        float diff = packed[c * TOTAL + i] - gbp[c];
        float ad = fabsf(diff);
        lc += (ad < 1.0f) ? 0.5f * ad * ad : (ad - 0.5f);
      }
      spp += log1pf(expf(-fabsf(x))) + fmaxf(-x, 0.0f);  // softplus(-x)
    } else {
      spn += log1pf(expf(-fabsf(x))) + fmaxf(x, 0.0f);   // softplus(x)
    }
  }
#pragma unroll
  for (int off = 32; off >= 1; off >>= 1) {
    lc += __shfl_down(lc, off);
    spp += __shfl_down(spp, off);
    spn += __shfl_down(spn, off);
    np += __shfl_down(np, off);
  }
  __shared__ float red[4][4];
  __shared__ int s_last;
  int wave = threadIdx.x >> 6;
  if ((threadIdx.x & 63) == 0) {
    red[wave][0] = lc; red[wave][1] = spp; red[wave][2] = spn; red[wave][3] = np;
  }
  __syncthreads();
  if (threadIdx.x == 0) {
    float o0 = 0, o1 = 0, o2 = 0, o3 = 0;
#pragma unroll
    for (int w = 0; w < 4; w++) { o0 += red[w][0]; o1 += red[w][1]; o2 += red[w][2]; o3 += red[w][3]; }
    float* p = &partials[(size_t)blockIdx.x * 8];
    __hip_atomic_store(&p[0], o0, __ATOMIC_RELAXED, __HIP_MEMORY_SCOPE_AGENT);
    __hip_atomic_store(&p[1], o1, __ATOMIC_RELAXED, __HIP_MEMORY_SCOPE_AGENT);
    __hip_atomic_store(&p[2], o2, __ATOMIC_RELAXED, __HIP_MEMORY_SCOPE_AGENT);
    __hip_atomic_store(&p[3], o3, __ATOMIC_RELAXED, __HIP_MEMORY_SCOPE_AGENT);
    __threadfence();
    int ticket = __hip_atomic_fetch_add(done, 1, __ATOMIC_ACQ_REL, __HIP_MEMORY_SCOPE_AGENT);
    s_last = (ticket == gridDim.x - 1) ? 1 : 0;
  }
  __syncthreads();
  if (s_last) {
    __threadfence();
    const int t = threadIdx.x;
    float l0 = __hip_atomic_load(&partials[t * 8 + 0], __ATOMIC_RELAXED, __HIP_MEMORY_SCOPE_AGENT);
    float l1 = __hip_atomic_load(&partials[t * 8 + 1], __ATOMIC_RELAXED, __HIP_MEMORY_SCOPE_AGENT);
    float l2 = __hip_atomic_load(&partials[t * 8 + 2], __ATOMIC_RELAXED, __HIP_MEMORY_SCOPE_AGENT);
    float l3 = __hip_atomic_load(&partials[t * 8 + 3], __ATOMIC_RELAXED, __HIP_MEMORY_SCOPE_AGENT);
#pragma unroll
    for (int off = 32; off >= 1; off >>= 1) {
      l0 += __shfl_down(l0, off);
      l1 += __shfl_down(l1, off);
      l2 += __shfl_down(l2, off);
      l3 += __shfl_down(l3, off);
    }
    __shared__ float red2[4][4];
    if ((t & 63) == 0) {
      red2[t >> 6][0] = l0; red2[t >> 6][1] = l1; red2[t >> 6][2] = l2; red2[t >> 6][3] = l3;
    }
    __syncthreads();
    if (t == 0) {
      float o0 = 0, o1 = 0, o2 = 0, o3 = 0;
#pragma unroll
      for (int w = 0; w < 4; w++) { o0 += red2[w][0]; o1 += red2[w][1]; o2 += red2[w][2]; o3 += red2[w][3]; }
      int ne = 0;
      for (int i = 0; i < NB * NS; i++) ne += bs_unm[i];
      float n_pos = o3;
      float loss_center = o0 / fmaxf(n_pos * 3.0f, 1.0f);
      float n_neg = (float)TOTAL - n_pos;
      float pw = fminf(10.0f, n_neg / fmaxf(n_pos, 1.0f));
      float loss_obj = (pw * o1 + o2) / (float)TOTAL;
      float loss_unm = acc[0] / fmaxf((float)ne, 1.0f);
      out[0] = loss_center * wc[0] + loss_obj * wo[0] + loss_unm * wu[0];
    }
  }
}

extern "C" void kernel_launch(void* const* d_in, const int* in_sizes, int n_in,
                              void* d_out, int out_size, void* d_ws, size_t ws_size,
                              hipStream_t stream) {
  const float* pred_boxes = (const float*)d_in[0];
  // d_in[1] = pred_classes (unused), d_in[4] = gt_classes (unused), d_in[9] = epoch (unused)
  const float* pred_scores = (const float*)d_in[2];
  const float* gt_boxes = (const float*)d_in[3];
  const int* n_gt = (const int*)d_in[5];
  const float* wc = (const float*)d_in[6];
  const float* wo = (const float*)d_in[7];
  const float* wu = (const float*)d_in[8];
  float* out = (float*)d_out;

  char* ws = (char*)d_ws;
  int* assign = (int*)ws;                                   // TOTAL ints (1 MB)
  float* packed = (float*)(ws + (size_t)TOTAL * 4);         // 3*TOTAL floats (3 MB)
  float* acc = (float*)(ws + (size_t)TOTAL * 16);           // acc[0] = per_gt_sum
  int* done = (int*)((char*)acc + 64);
  int* bs_unm = (int*)((char*)acc + 128);                   // NB*NS ints
  float* partials = (float*)((char*)acc + 512);             // LOSS_BLOCKS * 8 floats

  prep_kernel<<<512, 256, 0, stream>>>(pred_boxes, packed, assign, acc, bs_unm, done);
  topk_kernel<<<NB * NS * NM, TT, 0, stream>>>(packed, pred_scores, gt_boxes,
                                               n_gt, assign, &acc[0], bs_unm);
  loss_final_kernel<<<LOSS_BLOCKS, 256, 0, stream>>>(packed, pred_scores, gt_boxes, assign,
                                                     partials, done, acc, bs_unm, wc, wo, wu, out);
}